// Round 4
// baseline (311.664 us; speedup 1.0000x reference)
//
#include <hip/hip_runtime.h>

// Problem: N=32, W=64, H=64, C=256, D_STYLE=256. All fp32 in/out.
// out = leaky0.1( (inputs * softmax_c(colsum*q*s) * softmax_wh(inputs·q*s)) @ Wconv )
// Pipeline: style -> reduce_cast (2048 blk, full occupancy, prefetched stream)
// -> softmax_wscale (1024 thr) -> conv (BK=32 dbuf, 4 blk/CU). Round-4 change is
// ONLY the reduce pass (A/B vs round 3): 32 waves/CU + MLP>=2 + indep accumulators.

#define NBATCH 32
#define PIX 4096          // 64*64
#define CH 256
#define SCALE 0.0625f     // 1/sqrt(256)

typedef __attribute__((ext_vector_type(8))) short short8;
typedef __attribute__((ext_vector_type(4))) short short4v;
typedef __attribute__((ext_vector_type(4))) float floatx4;

__device__ __forceinline__ short f2bf(float x) {
    unsigned u = __builtin_bit_cast(unsigned, x);
    u += 0x7fffu + ((u >> 16) & 1u);   // round-to-nearest-even
    return (short)(u >> 16);
}

// async global->LDS, 16B per lane; LDS dest = wave-uniform base + lane*16
__device__ __forceinline__ void gll16(const void* g, void* l) {
    __builtin_amdgcn_global_load_lds(
        (const __attribute__((address_space(1))) unsigned int*)g,
        (__attribute__((address_space(3))) unsigned int*)l, 16, 0, 0);
}

// ---------------- K1: q = leaky_relu(style @ w_dense, 0.3) -------------------
__global__ __launch_bounds__(256) void style_kernel(
    const float* __restrict__ style, const float* __restrict__ wd,
    float* __restrict__ q)
{
    __shared__ float s[256];
    const int n = blockIdx.x, t = threadIdx.x;
    s[t] = style[n * 256 + t];
    __syncthreads();
    float acc = 0.f;
#pragma unroll 8
    for (int k = 0; k < 256; ++k) acc += s[k] * wd[k * 256 + t];
    q[n * 256 + t] = acc > 0.f ? acc : 0.3f * acc;
}

// ---------------- K2: streaming pass: colsum partials, pa_logits, bf16 cast --
// 2048 blocks (64 px each, 16 px/wave), LDS 17.2 KB -> 8 blocks/CU = 32 waves/CU.
// Explicit next-row prefetch + two independent accumulator quads (no serial chain).
__global__ __launch_bounds__(256) void reduce_cast(
    const float* __restrict__ inp, const float* __restrict__ q,
    float* __restrict__ colsum_part, float* __restrict__ pa_logits,
    short* __restrict__ bf16in)
{
    __shared__ float part[4][16][67];   // [wave][pixel][lane] f32, 17.2 KB
    const int n = blockIdx.y, chunk = blockIdx.x;   // 64 chunks of 64 px
    const int t = threadIdx.x, lane = t & 63, w = t >> 6;
    const float4 qv = *(const float4*)&q[n * 256 + lane * 4];
    const int pbase = chunk * 64 + w * 16;
    const float* base = inp + ((size_t)n * PIX + pbase) * CH;
    short* obase = bf16in + ((size_t)n * PIX + pbase) * CH;

    float4 cs0 = make_float4(0.f, 0.f, 0.f, 0.f);
    float4 cs1 = make_float4(0.f, 0.f, 0.f, 0.f);
    float4 v = *(const float4*)&base[lane * 4];
#pragma unroll
    for (int j = 0; j < 16; ++j) {
        float4 vn;
        if (j < 15) vn = *(const float4*)&base[(size_t)(j + 1) * CH + lane * 4];
        if (j & 1) { cs1.x += v.x; cs1.y += v.y; cs1.z += v.z; cs1.w += v.w; }
        else       { cs0.x += v.x; cs0.y += v.y; cs0.z += v.z; cs0.w += v.w; }
        part[w][j][lane] = v.x * qv.x + v.y * qv.y + v.z * qv.z + v.w * qv.w;
        short4v sv;
        sv.x = f2bf(v.x); sv.y = f2bf(v.y); sv.z = f2bf(v.z); sv.w = f2bf(v.w);
        *(short4v*)&obase[(size_t)j * CH + lane * 4] = sv;
        v = vn;
    }
    __syncthreads();
    // lane (p = l&15, seg = l>>4) sums 16 consecutive partials of pixel p
    const int p = lane & 15, seg = lane >> 4;
    float s = 0.f;
#pragma unroll
    for (int i = 0; i < 16; ++i) s += part[w][p][seg * 16 + i];
    s += __shfl_xor(s, 16);
    s += __shfl_xor(s, 32);
    if (lane < 16) pa_logits[n * PIX + pbase + lane] = s * SCALE;
    float4 cs = make_float4(cs0.x + cs1.x, cs0.y + cs1.y, cs0.z + cs1.z, cs0.w + cs1.w);
    *(float4*)&colsum_part[((size_t)n * 256 + chunk * 4 + w) * 256 + lane * 4] = cs;
}

// ---------------- K3: ca softmax; pa softmax; wscaled = bf16(diag(ca)@W)^T --
// 1024 threads, wave-level shfl reductions + 16-entry LDS combine.
__global__ __launch_bounds__(1024) void softmax_wscale(
    const float* __restrict__ colsum_part, const float* __restrict__ q,
    const float* __restrict__ pa_logits, const float* __restrict__ wc,
    float* __restrict__ pa, short* __restrict__ wscaled)
{
    __shared__ float red4[4][256];
    __shared__ float wred[16];
    __shared__ float ca_s[256];
    __shared__ float wt[32][257];
    const int n = blockIdx.x, t = threadIdx.x;
    const int lane = t & 63, wave = t >> 6;

    // ---- colsum: thread (seg, ch) sums 64 of 256 partial rows ----
    {
        const int ch = t & 255, seg = t >> 8;
        float c0 = 0.f;
#pragma unroll 8
        for (int i = 0; i < 64; ++i)
            c0 += colsum_part[((size_t)n * 256 + seg * 64 + i) * 256 + ch];
        red4[seg][ch] = c0;
    }
    __syncthreads();

    // ---- ca over 256 channels (threads 0..255 hold data) ----
    float lg = -1e30f, e = 0.f;
    if (t < 256) {
        float csum = red4[0][t] + red4[1][t] + red4[2][t] + red4[3][t];
        lg = csum * q[n * 256 + t] * SCALE;
    }
    float m = lg;
#pragma unroll
    for (int off = 32; off; off >>= 1) m = fmaxf(m, __shfl_xor(m, off));
    if (lane == 0) wred[wave] = m;
    __syncthreads();
    m = fmaxf(fmaxf(wred[0], wred[1]), fmaxf(wred[2], wred[3]));
    if (t < 256) e = expf(lg - m);
    float es = e;
#pragma unroll
    for (int off = 32; off; off >>= 1) es += __shfl_xor(es, off);
    __syncthreads();
    if (lane == 0) wred[wave] = es;
    __syncthreads();
    float S = wred[0] + wred[1] + wred[2] + wred[3];
    if (t < 256) ca_s[t] = e / S;

    // ---- pa over 4096 pixels, 4 per thread ----
    float lv[4], lmax = -1e30f;
#pragma unroll
    for (int i = 0; i < 4; ++i) {
        lv[i] = pa_logits[n * PIX + t + 1024 * i];
        lmax = fmaxf(lmax, lv[i]);
    }
#pragma unroll
    for (int off = 32; off; off >>= 1) lmax = fmaxf(lmax, __shfl_xor(lmax, off));
    __syncthreads();
    if (lane == 0) wred[wave] = lmax;
    __syncthreads();
    float M = wred[0];
#pragma unroll
    for (int i = 1; i < 16; ++i) M = fmaxf(M, wred[i]);
    float ev[4], lsum = 0.f;
#pragma unroll
    for (int i = 0; i < 4; ++i) { ev[i] = expf(lv[i] - M); lsum += ev[i]; }
#pragma unroll
    for (int off = 32; off; off >>= 1) lsum += __shfl_xor(lsum, off);
    __syncthreads();
    if (lane == 0) wred[wave] = lsum;
    __syncthreads();
    float Ssum = 0.f;
#pragma unroll
    for (int i = 0; i < 16; ++i) Ssum += wred[i];
    float inv = 1.0f / Ssum;
#pragma unroll
    for (int i = 0; i < 4; ++i) pa[n * PIX + t + 1024 * i] = ev[i] * inv;

    // ---- wscaled[n][co][ci] = bf16(wc[ci][co] * ca[ci]), 8 ci-strips of 32 --
    const int tx = t & 31;
    for (int strip = 0; strip < 8; ++strip) {
        const int ci0 = strip * 32;
        __syncthreads();
#pragma unroll
        for (int r = 0; r < 8; ++r) {
            const int idx = t + 1024 * r;               // 8192 elems / strip
            wt[idx >> 8][idx & 255] = wc[(ci0 + (idx >> 8)) * 256 + (idx & 255)];
        }
        __syncthreads();
        const float cav = ca_s[ci0 + tx];
#pragma unroll
        for (int r = 0; r < 8; ++r) {
            const int co = r * 32 + (t >> 5);
            wscaled[(size_t)n * 65536 + co * 256 + ci0 + tx] = f2bf(wt[tx][co] * cav);
        }
    }
}

// ---------------- K4: y = leaky0.1( (bf16in @ wscaled^T) .* pa ) ------------
// Tile 64 pixels x 256 co, BK=32 double-buffered: LDS 40 KB -> 4 blocks/CU
// (16 waves/CU). Swizzle: slot ^= (row>>1)&3 -> 2-way conflicts (free) on
// both the linear gll16 stage (pre-swizzled source) and the ds_read_b128.
__global__ __launch_bounds__(256, 4) void conv_mfma(
    const short* __restrict__ bf16in, const short* __restrict__ wscaled,
    const float* __restrict__ pa, float* __restrict__ out)
{
    __shared__ __attribute__((aligned(16))) short As[2][64 * 32];    //  8 KB
    __shared__ __attribute__((aligned(16))) short Bs[2][256 * 32];   // 32 KB

    const int n  = blockIdx.y;
    const int m0 = blockIdx.x * 64;     // pixel base
    const int tid = threadIdx.x;
    const int lane = tid & 63, wid = tid >> 6;
    const int l16 = lane & 15, quad = lane >> 4;
    const int r4 = lane >> 2, s4 = lane & 3;   // staging: row-in-16, 16B slot

    floatx4 acc[4][4] = {};

    const short* Agb = bf16in + ((size_t)n * PIX + m0) * CH;
    const short* Bgb = wscaled + (size_t)n * 65536;

    auto stage = [&](int kb, int buf) {
        const int k0 = kb * 32;
        // A: 64 rows x 32 k = 4 KB; 1 instr per wave covers 16 rows
        {
            const int r = wid * 16 + r4;
            gll16(Agb + (size_t)r * CH + k0 + ((s4 ^ ((r >> 1) & 3)) << 3),
                  &As[buf][(wid * 16) * 32]);
        }
        // B: 256 rows x 32 k = 16 KB; 4 instrs per wave
#pragma unroll
        for (int i = 0; i < 4; ++i) {
            const int c = wid * 64 + i * 16 + r4;
            gll16(Bgb + (size_t)c * CH + k0 + ((s4 ^ ((c >> 1) & 3)) << 3),
                  &Bs[buf][(wid * 64 + i * 16) * 32]);
        }
    };

    stage(0, 0);
    __syncthreads();                       // buf0 ready

    for (int kb = 0; kb < 8; ++kb) {
        const int cur = kb & 1;
        if (kb < 7) stage(kb + 1, cur ^ 1);   // issue next tile BEFORE compute
        short8 af[4], bfr[4];
#pragma unroll
        for (int mt = 0; mt < 4; ++mt) {
            const int row = mt * 16 + l16;
            af[mt] = *(const short8*)&As[cur][row * 32 + ((quad ^ ((row >> 1) & 3)) << 3)];
        }
#pragma unroll
        for (int nt = 0; nt < 4; ++nt) {
            const int row = wid * 64 + nt * 16 + l16;
            bfr[nt] = *(const short8*)&Bs[cur][row * 32 + ((quad ^ ((row >> 1) & 3)) << 3)];
        }
#pragma unroll
        for (int mt = 0; mt < 4; ++mt)
#pragma unroll
            for (int nt = 0; nt < 4; ++nt)
                acc[mt][nt] = __builtin_amdgcn_mfma_f32_16x16x32_bf16(
                    af[mt], bfr[nt], acc[mt][nt], 0, 0, 0);
        __syncthreads();   // drains next-tile loads (issued before compute)
    }

    // epilogue: z = acc * pa[pixel]; leaky 0.1; store
#pragma unroll
    for (int mt = 0; mt < 4; ++mt) {
#pragma unroll
        for (int reg = 0; reg < 4; ++reg) {
            const int pix = m0 + mt * 16 + quad * 4 + reg;
            const float pav = pa[n * PIX + pix];
            float* orow = out + ((size_t)(n * PIX + pix)) * CH + wid * 64;
#pragma unroll
            for (int nt = 0; nt < 4; ++nt) {
                float z = acc[mt][nt][reg] * pav;
                orow[nt * 16 + l16] = z > 0.f ? z : 0.1f * z;
            }
        }
    }
}

extern "C" void kernel_launch(void* const* d_in, const int* in_sizes, int n_in,
                              void* d_out, int out_size, void* d_ws, size_t ws_size,
                              hipStream_t stream) {
    const float* inputs = (const float*)d_in[0];   // [32,64,64,256]
    const float* style  = (const float*)d_in[1];   // [32,256]
    const float* wdense = (const float*)d_in[2];   // [256,256]
    const float* wconv  = (const float*)d_in[3];   // [1,1,256,256] = [ci][co]
    float* out = (float*)d_out;

    // workspace layout (bytes)
    char* ws = (char*)d_ws;
    float* q           = (float*)(ws + 0);          //  32 KB
    float* pa_logits   = (float*)(ws + 32768);      // 512 KB
    float* pa          = (float*)(ws + 557056);     // 512 KB
    float* colsum_part = (float*)(ws + 1081344);    //   8 MB  [32][256][256] f32
    short* wscaled     = (short*)(ws + 9469952);    //   4 MB  [32][256][256] bf16
    short* bf16in      = (short*)(ws + 13664256);   //  64 MB  [32][4096][256] bf16

    style_kernel<<<NBATCH, 256, 0, stream>>>(style, wdense, q);
    reduce_cast<<<dim3(64, NBATCH), 256, 0, stream>>>(inputs, q, colsum_part,
                                                      pa_logits, bf16in);
    softmax_wscale<<<NBATCH, 1024, 0, stream>>>(colsum_part, q, pa_logits, wconv,
                                                pa, wscaled);
    conv_mfma<<<dim3(64, NBATCH), 256, 0, stream>>>(bf16in, wscaled, pa, out);
}